// Round 5
// baseline (186.055 us; speedup 1.0000x reference)
//
#include <hip/hip_runtime.h>
#include <cmath>

// Shapes fixed by reference: R=4096, F=256, K=8.
#define R 4096
#define F 256
#define NK 8

typedef _Float16 half8 __attribute__((ext_vector_type(8)));
typedef _Float16 half4v __attribute__((ext_vector_type(4)));
typedef float f32x4 __attribute__((ext_vector_type(4)));

#define LOG2E      1.4426950408889634f
#define LOG2LOG2E  0.5287663729448977f   // log2(log2(e))

// ---------------------------------------------------------------------------
// ws layout (bytes):
//   0          : x1h (4096*256 f16) 2 MB
//   2 MB       : x2h (4096*256 f16) 2 MB
//   4 MB +0    : S   (8*4096 f32)  softmax denominators (phase-0 atomics)
//       +128K  : rA  (8*4096 f32)  c_k*(sq1-2m r1+Fm^2)+log2log2e
//       +256K  : cB  (8*4096 f32)  c_k*(sq2+2m r2)
//       +384K  : prm (16 f32) [0..7]=w_k  [8..15]=g_k = 2*is2*log2e
// Math: c_k = -log2e/(2 s_k^2); t = rA[k][i]+cB[k][j]+g_k*dot,  g_k = -2 c_k
//       exp(kv) = exp2(exp2(t)).  dist in [~150,~6600] so ref clamps never bind.
// ---------------------------------------------------------------------------

// prep: fp16 cast + row sums (butterfly leaves s,q in ALL lanes) + rA/cB
// directly from lanes 0..7, + S zeroing + k-param table. One kernel.
__global__ __launch_bounds__(256) void prep_kernel(
    const float* __restrict__ x1, const float* __restrict__ x2,
    const float* __restrict__ sigmas, const float* __restrict__ means,
    const float* __restrict__ sigp,
    _Float16* __restrict__ x1h, _Float16* __restrict__ x2h,
    float* __restrict__ rA, float* __restrict__ cB,
    float* __restrict__ S, float* __restrict__ prm)
{
    const int tid  = threadIdx.x;
    const int wid  = tid >> 6;
    const int lane = tid & 63;
    const int row  = blockIdx.x * 4 + wid;   // 0..8191: x1 rows then x2 rows

    const float* src; _Float16* dsth; int r; bool isX1;
    if (row < R) { src = x1; dsth = x1h; r = row;     isX1 = true;  }
    else         { src = x2; dsth = x2h; r = row - R; isX1 = false; }

    float4 v = ((const float4*)(src + (size_t)r * F))[lane];
    half4v h = { (_Float16)v.x, (_Float16)v.y, (_Float16)v.z, (_Float16)v.w };
    *(half4v*)(dsth + (size_t)r * F + lane * 4) = h;

    float s = v.x + v.y + v.z + v.w;
    float q = v.x * v.x + v.y * v.y + v.z * v.z + v.w * v.w;
    for (int m = 1; m < 64; m <<= 1) {
        s += __shfl_xor(s, m);
        q += __shfl_xor(q, m);
    }
    // all lanes now hold row totals; lanes 0..7 emit the 8 per-k row terms
    if (lane < NK) {
        int k = lane;
        float sg = sigmas[k], m = means[k];
        float c  = -LOG2E / (2.f * sg * sg);         // c_k
        if (isX1) rA[k * R + r] = c * (q - 2.f * m * s + (float)F * m * m) + LOG2LOG2E;
        else      cB[k * R + r] = c * (q + 2.f * m * s);
    }

    int g = blockIdx.x * 256 + tid;
    if (g < NK * R) S[g] = 0.f;   // ws re-poisoned 0xAA each call

    if (blockIdx.x == 0 && tid == 0) {
        float w[NK], mx = -1e30f;
        for (int k = 0; k < NK; ++k) { float sp = sigp[k]; w[k] = 1.f / (sp * sp); mx = fmaxf(mx, w[k]); }
        float sum = 0.f;
        for (int k = 0; k < NK; ++k) { w[k] = expf(w[k] - mx); sum += w[k]; }
        for (int k = 0; k < NK; ++k) prm[k] = w[k] / sum;
        for (int k = 0; k < NK; ++k) {
            float sg = sigmas[k];
            prm[8 + k] = LOG2E / (sg * sg);     // g_k = 2*is2*log2e
        }
    }
}

// ---------------------------------------------------------------------------
// 128x128-tile fp16 MFMA GEMM (dot = x1 @ x2^T) + fused exp2 epilogue.
// Geometry frozen at R4's operating point: (256,2), VGPR~64, 3 blocks/CU.
// Epilogue flattened to 16 iterations with next-iteration rA (+S) prefetch:
// each iter's ~200cy L1/L2 load batch now overlaps the previous iter's
// ~450cy of VALU+trans instead of head-blocking it.
// PHASE 0: S[k,i] += sum_j exp2(exp2(t))   (quad-shuffle + atomicAdd)
// PHASE 1: out[i,j] = sum_k w_k*rcp(S[k,i]) * exp2(exp2(t))  (finalize folded in)
// ---------------------------------------------------------------------------
template <int PHASE>
__global__ __launch_bounds__(256, 2) void gemm_kernel(
    const _Float16* __restrict__ Ah, const _Float16* __restrict__ Bh,
    const float* __restrict__ rA, const float* __restrict__ cB,
    const float* __restrict__ prm, float* __restrict__ S, float* __restrict__ out)
{
    constexpr int SK = 72;  // 64 + 8-half pad: 2-way bank alias (free)
    __shared__ _Float16 As[128 * SK];
    __shared__ _Float16 Bs[128 * SK];

    const int tid  = threadIdx.x;
    const int lane = tid & 63;
    const int wid  = tid >> 6;
    const int wm   = wid >> 1, wn = wid & 1;   // 2x2 waves of 64x64
    const int q    = lane >> 4, m16 = lane & 15;
    const int tm   = blockIdx.y, tn = blockIdx.x;

    f32x4 acc[4][4];
#pragma unroll
    for (int a = 0; a < 4; ++a)
#pragma unroll
        for (int b = 0; b < 4; ++b)
            acc[a][b] = (f32x4){0.f, 0.f, 0.f, 0.f};

    for (int k0 = 0; k0 < F; k0 += 64) {
#pragma unroll
        for (int c = 0; c < 4; ++c) {
            int idx = c * 256 + tid;         // 0..1023 chunks of 8 halves
            int row = idx >> 3, c8 = (idx & 7) * 8;
            *(uint4*)&As[row * SK + c8] =
                *(const uint4*)&Ah[(size_t)(tm * 128 + row) * F + k0 + c8];
            *(uint4*)&Bs[row * SK + c8] =
                *(const uint4*)&Bh[(size_t)(tn * 128 + row) * F + k0 + c8];
        }
        __syncthreads();
#pragma unroll
        for (int s = 0; s < 2; ++s) {
            half8 a[4], b[4];
#pragma unroll
            for (int mt = 0; mt < 4; ++mt)
                a[mt] = *(const half8*)&As[(wm * 64 + mt * 16 + m16) * SK + s * 32 + q * 8];
#pragma unroll
            for (int nt = 0; nt < 4; ++nt)
                b[nt] = *(const half8*)&Bs[(wn * 64 + nt * 16 + m16) * SK + s * 32 + q * 8];
#pragma unroll
            for (int mt = 0; mt < 4; ++mt)
#pragma unroll
                for (int nt = 0; nt < 4; ++nt)
                    acc[mt][nt] = __builtin_amdgcn_mfma_f32_16x16x32_f16(
                        a[mt], b[nt], acc[mt][nt], 0, 0, 0);
        }
        __syncthreads();
    }

    // ---- epilogue ----
    float g[8], wv[8];
#pragma unroll
    for (int k = 0; k < 8; ++k) g[k] = prm[8 + k];   // uniform -> SGPR
    if (PHASE == 1) {
#pragma unroll
        for (int k = 0; k < 8; ++k) wv[k] = prm[k];
    }

    int colg[4];
    float colQ[8][4];
#pragma unroll
    for (int nt = 0; nt < 4; ++nt) {
        colg[nt] = tn * 128 + wn * 64 + nt * 16 + m16;
#pragma unroll
        for (int k = 0; k < 8; ++k) colQ[k][nt] = cB[k * R + colg[nt]];
    }

    const int rowb = tm * 128 + wm * 64 + q * 4;   // rowg = rowb + mt*16 + r
    float rAv[8], Sv[8];
#pragma unroll
    for (int k = 0; k < 8; ++k) {
        rAv[k] = rA[k * R + rowb];
        if (PHASE == 1) Sv[k] = S[k * R + rowb];
    }

#pragma unroll
    for (int it = 0; it < 16; ++it) {
        const int mt = it >> 2, r = it & 3;
        const int rowg = rowb + mt * 16 + r;

        // prefetch next iteration's row operands
        float rAn[8], Sn[8];
        if (it < 15) {
            const int itn = it + 1;
            const int rowgn = rowb + (itn >> 2) * 16 + (itn & 3);
#pragma unroll
            for (int k = 0; k < 8; ++k) {
                rAn[k] = rA[k * R + rowgn];
                if (PHASE == 1) Sn[k] = S[k * R + rowgn];
            }
        }

        if (PHASE == 0) {
            float tk[8];
#pragma unroll
            for (int k = 0; k < 8; ++k) tk[k] = 0.f;
#pragma unroll
            for (int nt = 0; nt < 4; ++nt) {
                float d = acc[mt][nt][r];
#pragma unroll
                for (int k = 0; k < 8; ++k) {
                    float t = fmaf(g[k], d, rAv[k] + colQ[k][nt]);
                    tk[k] += __builtin_amdgcn_exp2f(__builtin_amdgcn_exp2f(t));
                }
            }
#pragma unroll
            for (int k = 0; k < 8; ++k) {
                float t = tk[k];
                t += __shfl_xor(t, 1); t += __shfl_xor(t, 2);
                t += __shfl_xor(t, 4); t += __shfl_xor(t, 8);
                if (m16 == 0) atomicAdd(&S[k * R + rowg], t);
            }
        } else {
            float sv[8];
#pragma unroll
            for (int k = 0; k < 8; ++k)
                sv[k] = wv[k] * __builtin_amdgcn_rcpf(Sv[k]);   // w_k/denom
#pragma unroll
            for (int nt = 0; nt < 4; ++nt) {
                float d = acc[mt][nt][r];
                float o = 0.f;
#pragma unroll
                for (int k = 0; k < 8; ++k) {
                    float t = fmaf(g[k], d, rAv[k] + colQ[k][nt]);
                    o = fmaf(sv[k], __builtin_amdgcn_exp2f(__builtin_amdgcn_exp2f(t)), o);
                }
                __builtin_nontemporal_store(o, &out[(size_t)rowg * R + colg[nt]]);
            }
        }

        if (it < 15) {
#pragma unroll
            for (int k = 0; k < 8; ++k) {
                rAv[k] = rAn[k];
                if (PHASE == 1) Sv[k] = Sn[k];
            }
        }
    }
}

extern "C" void kernel_launch(void* const* d_in, const int* in_sizes, int n_in,
                              void* d_out, int out_size, void* d_ws, size_t ws_size,
                              hipStream_t stream) {
    (void)in_sizes; (void)n_in; (void)out_size; (void)ws_size;
    const float* x1     = (const float*)d_in[0];
    const float* x2     = (const float*)d_in[1];
    const float* sigmas = (const float*)d_in[2];
    const float* means  = (const float*)d_in[3];
    const float* sigp   = (const float*)d_in[4];
    float* out = (float*)d_out;

    char* ws = (char*)d_ws;
    _Float16* x1h = (_Float16*)ws;
    _Float16* x2h = (_Float16*)(ws + 2097152);
    float* S   = (float*)(ws + 4194304);
    float* rA  = (float*)(ws + 4194304 + 131072);
    float* cB  = (float*)(ws + 4194304 + 262144);
    float* prm = (float*)(ws + 4194304 + 393216);

    prep_kernel<<<2048, 256, 0, stream>>>(x1, x2, sigmas, means, sigp,
                                          x1h, x2h, rA, cB, S, prm);
    gemm_kernel<0><<<dim3(32, 32), 256, 0, stream>>>(x1h, x2h, rA, cB, prm, S, out);
    gemm_kernel<1><<<dim3(32, 32), 256, 0, stream>>>(x1h, x2h, rA, cB, prm, S, out);
}

// Round 6
// 180.240 us; speedup vs baseline: 1.0323x; 1.0323x over previous
//
#include <hip/hip_runtime.h>
#include <cmath>

// Shapes fixed by reference: R=4096, F=256, K=8.
#define R 4096
#define F 256
#define NK 8

typedef _Float16 half8 __attribute__((ext_vector_type(8)));
typedef _Float16 half4v __attribute__((ext_vector_type(4)));
typedef float f32x4 __attribute__((ext_vector_type(4)));

#define LOG2E      1.4426950408889634f
#define LOG2LOG2E  0.5287663729448977f   // log2(log2(e))

// ---------------------------------------------------------------------------
// ws layout (bytes):
//   0          : x1h (4096*256 f16) 2 MB
//   2 MB       : x2h (4096*256 f16) 2 MB
//   4 MB +0    : S   (8*4096 f32)  softmax denominators (phase-0 atomics)
//       +128K  : rA  (8*4096 f32)  c_k*(sq1-2m r1+Fm^2)+log2log2e
//       +256K  : cB  (8*4096 f32)  c_k*(sq2+2m r2)
//       +384K  : prm (16 f32) [0..7]=w_k  [8..15]=g_k = 2*is2*log2e
// Math: c_k = -log2e/(2 s_k^2); t = rA[k][i]+cB[k][j]+g_k*dot,  g_k = -2 c_k
//       exp(kv) = exp2(exp2(t)).  dist in [~150,~6600] so ref clamps never bind.
// ---------------------------------------------------------------------------

// prep: fp16 cast + row sums (butterfly leaves s,q in ALL lanes) + rA/cB
// directly from lanes 0..7, + S zeroing + k-param table. One kernel.
__global__ __launch_bounds__(256) void prep_kernel(
    const float* __restrict__ x1, const float* __restrict__ x2,
    const float* __restrict__ sigmas, const float* __restrict__ means,
    const float* __restrict__ sigp,
    _Float16* __restrict__ x1h, _Float16* __restrict__ x2h,
    float* __restrict__ rA, float* __restrict__ cB,
    float* __restrict__ S, float* __restrict__ prm)
{
    const int tid  = threadIdx.x;
    const int wid  = tid >> 6;
    const int lane = tid & 63;
    const int row  = blockIdx.x * 4 + wid;   // 0..8191: x1 rows then x2 rows

    const float* src; _Float16* dsth; int r; bool isX1;
    if (row < R) { src = x1; dsth = x1h; r = row;     isX1 = true;  }
    else         { src = x2; dsth = x2h; r = row - R; isX1 = false; }

    float4 v = ((const float4*)(src + (size_t)r * F))[lane];
    half4v h = { (_Float16)v.x, (_Float16)v.y, (_Float16)v.z, (_Float16)v.w };
    *(half4v*)(dsth + (size_t)r * F + lane * 4) = h;

    float s = v.x + v.y + v.z + v.w;
    float q = v.x * v.x + v.y * v.y + v.z * v.z + v.w * v.w;
    for (int m = 1; m < 64; m <<= 1) {
        s += __shfl_xor(s, m);
        q += __shfl_xor(q, m);
    }
    // all lanes hold row totals; lanes 0..7 emit the 8 per-k row terms
    if (lane < NK) {
        int k = lane;
        float sg = sigmas[k], m = means[k];
        float c  = -LOG2E / (2.f * sg * sg);         // c_k
        if (isX1) rA[k * R + r] = c * (q - 2.f * m * s + (float)F * m * m) + LOG2LOG2E;
        else      cB[k * R + r] = c * (q + 2.f * m * s);
    }

    int g = blockIdx.x * 256 + tid;
    if (g < NK * R) S[g] = 0.f;   // ws re-poisoned 0xAA each call

    if (blockIdx.x == 0 && tid == 0) {
        float w[NK], mx = -1e30f;
        for (int k = 0; k < NK; ++k) { float sp = sigp[k]; w[k] = 1.f / (sp * sp); mx = fmaxf(mx, w[k]); }
        float sum = 0.f;
        for (int k = 0; k < NK; ++k) { w[k] = expf(w[k] - mx); sum += w[k]; }
        for (int k = 0; k < NK; ++k) prm[k] = w[k] / sum;
        for (int k = 0; k < NK; ++k) {
            float sg = sigmas[k];
            prm[8 + k] = LOG2E / (sg * sg);     // g_k = 2*is2*log2e
        }
    }
}

// ---------------------------------------------------------------------------
// 128x128-tile fp16 MFMA GEMM (dot = x1 @ x2^T) + fused exp2 epilogue.
// EXACT R4 epilogue shape (VGPR=64 -> 3 blocks/CU; R5's prefetch regs pushed
// VGPR to 96 and halved occupancy -- do not reintroduce).
// PHASE 0: S[k,i] += sum_j exp2(exp2(t))   (quad-shuffle + atomicAdd)
// PHASE 1: out[i,j] = sum_k w_k*rcp(S[k,i]) * exp2(exp2(t))  (finalize folded)
// ---------------------------------------------------------------------------
template <int PHASE>
__global__ __launch_bounds__(256, 2) void gemm_kernel(
    const _Float16* __restrict__ Ah, const _Float16* __restrict__ Bh,
    const float* __restrict__ rA, const float* __restrict__ cB,
    const float* __restrict__ prm, float* __restrict__ S, float* __restrict__ out)
{
    constexpr int SK = 72;  // 64 + 8-half pad: 2-way bank alias (free)
    __shared__ _Float16 As[128 * SK];
    __shared__ _Float16 Bs[128 * SK];

    const int tid  = threadIdx.x;
    const int lane = tid & 63;
    const int wid  = tid >> 6;
    const int wm   = wid >> 1, wn = wid & 1;   // 2x2 waves of 64x64
    const int q    = lane >> 4, m16 = lane & 15;
    const int tm   = blockIdx.y, tn = blockIdx.x;

    f32x4 acc[4][4];
#pragma unroll
    for (int a = 0; a < 4; ++a)
#pragma unroll
        for (int b = 0; b < 4; ++b)
            acc[a][b] = (f32x4){0.f, 0.f, 0.f, 0.f};

    for (int k0 = 0; k0 < F; k0 += 64) {
#pragma unroll
        for (int c = 0; c < 4; ++c) {
            int idx = c * 256 + tid;         // 0..1023 chunks of 8 halves
            int row = idx >> 3, c8 = (idx & 7) * 8;
            *(uint4*)&As[row * SK + c8] =
                *(const uint4*)&Ah[(size_t)(tm * 128 + row) * F + k0 + c8];
            *(uint4*)&Bs[row * SK + c8] =
                *(const uint4*)&Bh[(size_t)(tn * 128 + row) * F + k0 + c8];
        }
        __syncthreads();
#pragma unroll
        for (int s = 0; s < 2; ++s) {
            half8 a[4], b[4];
#pragma unroll
            for (int mt = 0; mt < 4; ++mt)
                a[mt] = *(const half8*)&As[(wm * 64 + mt * 16 + m16) * SK + s * 32 + q * 8];
#pragma unroll
            for (int nt = 0; nt < 4; ++nt)
                b[nt] = *(const half8*)&Bs[(wn * 64 + nt * 16 + m16) * SK + s * 32 + q * 8];
#pragma unroll
            for (int mt = 0; mt < 4; ++mt)
#pragma unroll
                for (int nt = 0; nt < 4; ++nt)
                    acc[mt][nt] = __builtin_amdgcn_mfma_f32_16x16x32_f16(
                        a[mt], b[nt], acc[mt][nt], 0, 0, 0);
        }
        __syncthreads();
    }

    // ---- epilogue (R4 shape) ----
    float g[8], wv[8];
#pragma unroll
    for (int k = 0; k < 8; ++k) g[k] = prm[8 + k];   // uniform -> SGPR
    if (PHASE == 1) {
#pragma unroll
        for (int k = 0; k < 8; ++k) wv[k] = prm[k];  // uniform -> SGPR
    }

    int colg[4];
    float colQ[8][4];
#pragma unroll
    for (int nt = 0; nt < 4; ++nt) {
        colg[nt] = tn * 128 + wn * 64 + nt * 16 + m16;
#pragma unroll
        for (int k = 0; k < 8; ++k) colQ[k][nt] = cB[k * R + colg[nt]];
    }

#pragma unroll
    for (int mt = 0; mt < 4; ++mt) {
#pragma unroll
        for (int r = 0; r < 4; ++r) {
            int rowg = tm * 128 + wm * 64 + mt * 16 + q * 4 + r;
            float rAv[8];
#pragma unroll
            for (int k = 0; k < 8; ++k) rAv[k] = rA[k * R + rowg];

            if (PHASE == 0) {
#pragma unroll
                for (int k = 0; k < 8; ++k) {
                    float t = 0.f;
#pragma unroll
                    for (int nt = 0; nt < 4; ++nt) {
                        float tt = fmaf(g[k], acc[mt][nt][r], rAv[k] + colQ[k][nt]);
                        t += __builtin_amdgcn_exp2f(__builtin_amdgcn_exp2f(tt));
                    }
                    t += __shfl_xor(t, 1); t += __shfl_xor(t, 2);
                    t += __shfl_xor(t, 4); t += __shfl_xor(t, 8);
                    if (m16 == 0) atomicAdd(&S[k * R + rowg], t);
                }
            } else {
                float sv[8];
#pragma unroll
                for (int k = 0; k < 8; ++k)
                    sv[k] = wv[k] * __builtin_amdgcn_rcpf(S[k * R + rowg]);
#pragma unroll
                for (int nt = 0; nt < 4; ++nt) {
                    float d = acc[mt][nt][r];
                    float o = 0.f;
#pragma unroll
                    for (int k = 0; k < 8; ++k) {
                        float tt = fmaf(g[k], d, rAv[k] + colQ[k][nt]);
                        o = fmaf(sv[k], __builtin_amdgcn_exp2f(__builtin_amdgcn_exp2f(tt)), o);
                    }
                    __builtin_nontemporal_store(o, &out[(size_t)rowg * R + colg[nt]]);
                }
            }
        }
    }
}

extern "C" void kernel_launch(void* const* d_in, const int* in_sizes, int n_in,
                              void* d_out, int out_size, void* d_ws, size_t ws_size,
                              hipStream_t stream) {
    (void)in_sizes; (void)n_in; (void)out_size; (void)ws_size;
    const float* x1     = (const float*)d_in[0];
    const float* x2     = (const float*)d_in[1];
    const float* sigmas = (const float*)d_in[2];
    const float* means  = (const float*)d_in[3];
    const float* sigp   = (const float*)d_in[4];
    float* out = (float*)d_out;

    char* ws = (char*)d_ws;
    _Float16* x1h = (_Float16*)ws;
    _Float16* x2h = (_Float16*)(ws + 2097152);
    float* S   = (float*)(ws + 4194304);
    float* rA  = (float*)(ws + 4194304 + 131072);
    float* cB  = (float*)(ws + 4194304 + 262144);
    float* prm = (float*)(ws + 4194304 + 393216);

    prep_kernel<<<2048, 256, 0, stream>>>(x1, x2, sigmas, means, sigp,
                                          x1h, x2h, rA, cB, S, prm);
    gemm_kernel<0><<<dim3(32, 32), 256, 0, stream>>>(x1h, x2h, rA, cB, prm, S, out);
    gemm_kernel<1><<<dim3(32, 32), 256, 0, stream>>>(x1h, x2h, rA, cB, prm, S, out);
}